// Round 3
// baseline (203.993 us; speedup 1.0000x reference)
//
#include <hip/hip_runtime.h>
#include <math.h>

#define BQ 8
#define MQ 64
#define REGMAX 16
#define KTOP 10
#define CH 4
#define EPSQ 1e-7f
#define SSEG 4
#define TRIG 256
#define CBUF (TRIG + SSEG * 256 + 16)  // 1296 slots; max fill = TRIG + SSEG*256 = 1280

__device__ __forceinline__ float frcp(float x) { return __builtin_amdgcn_rcpf(x); }

// ---------------- decode: DFL softmax EV + pred atan + iou zero-init + bce(s,0) ----------------
__global__ __launch_bounds__(256) void decode_kernel(
    const float* __restrict__ boxes, const float* __restrict__ scores,
    float* __restrict__ pb, float* __restrict__ patan,
    unsigned int* __restrict__ iou_bits, float* __restrict__ acc, int N) {
  const int tid = threadIdx.x;
  const int i = blockIdx.x * 256 + tid;
  const int total = BQ * N;
  float bce0 = 0.f;
  int myb = -1;
  const int b_first = (blockIdx.x * 256) / N;
  if (i < total) {
    iou_bits[i] = 0u;
    myb = i / N;
    int n = i - myb * N;
    float sc = scores[i];
    bce0 = fmaxf(sc, 0.f) + log1pf(__expf(-fabsf(sc)));
    const float* base = boxes + (size_t)myb * (4 * REGMAX) * N + n;
    float out[4];
#pragma unroll
    for (int k = 0; k < 4; ++k) {
      float x[REGMAX];
#pragma unroll
      for (int r = 0; r < REGMAX; ++r)
        x[r] = __builtin_nontemporal_load(&base[(size_t)(k * REGMAX + r) * N]);
      float mx = x[0];
#pragma unroll
      for (int r = 1; r < REGMAX; ++r) mx = fmaxf(mx, x[r]);
      float s = 0.f, ws = 0.f;
#pragma unroll
      for (int r = 0; r < REGMAX; ++r) {
        float e = __expf(x[r] - mx);
        s += e;
        ws += (float)r * e;
      }
      out[k] = ws * frcp(s);
    }
    ((float4*)pb)[i] = make_float4(out[0], out[1], out[2], out[3]);
    float w1 = out[2] - out[0], h1 = out[3] - out[1];
    patan[i] = atanf(w1 * frcp(h1 + EPSQ));
  }
  // block-reduce bce0, split across the (at most 2) batches this block straddles
  __shared__ float r0[256], r1[256];
  r0[tid] = (myb == b_first) ? bce0 : 0.f;
  r1[tid] = (myb == b_first + 1) ? bce0 : 0.f;
  __syncthreads();
  for (int s = 128; s > 0; s >>= 1) {
    if (tid < s) { r0[tid] += r0[tid + s]; r1[tid] += r1[tid + s]; }
    __syncthreads();
  }
  if (tid == 0) {
    atomicAdd(&acc[b_first * 4 + 2], r0[0]);
    if (b_first + 1 < BQ) atomicAdd(&acc[(b_first + 1) * 4 + 2], r1[0]);
  }
}

// ---------------- exact top-10 of LDS buffer (wave 0 only) ----------------
__device__ __forceinline__ void select_top10(
    float* s_bv, int* s_bi, float* s_winv, int* s_wini,
    int* s_cnt, float* s_sthr, int c, int tid) {
  if (tid < 64) {
    for (int r = 0; r < KTOP; ++r) {
      float bv = 0.f;
      int bs = 0xffff;
      for (int sl = tid; sl < c; sl += 64) {
        float v = s_bv[sl];
        if (v > bv) { bv = v; bs = sl; }
      }
      unsigned long long key =
          ((unsigned long long)__float_as_uint(bv) << 32) | (unsigned int)bs;
#pragma unroll
      for (int d = 1; d < 64; d <<= 1) {
        unsigned long long o = __shfl_xor(key, d, 64);
        if (o > key) key = o;
      }
      if (tid == 0) {
        float wv = __uint_as_float((unsigned int)(key >> 32));
        int ws = (int)(key & 0xffffu);
        s_winv[r] = wv;
        if (wv > 0.f && ws != 0xffff) {
          s_wini[r] = s_bi[ws];
          s_bv[ws] = 0.f;  // kill; wave-synchronous visibility for next round
        } else {
          s_wini[r] = 0;
        }
      }
    }
    if (tid < KTOP) { s_bv[tid] = s_winv[tid]; s_bi[tid] = s_wini[tid]; }
    if (tid == 0) { *s_cnt = KTOP; *s_sthr = s_winv[KTOP - 1]; }
  }
}

// ---------------- topk phase 1: (b,m,chunk) blocks, threshold + buffer ----------------
__global__ __launch_bounds__(256) void topk1_kernel(
    const float4* __restrict__ pb, const float* __restrict__ patan,
    const float* __restrict__ targets, float* __restrict__ cand_v,
    int* __restrict__ cand_i, int N) {
  const int blk = blockIdx.x;
  const int chunk = blk & (CH - 1);
  const int bm = blk >> 2;
  const int b = bm >> 6;
  const int m = bm & 63;
  const int tid = threadIdx.x;

  __shared__ float s_bv[CBUF];
  __shared__ int s_bi[CBUF];
  __shared__ float s_winv[KTOP];
  __shared__ int s_wini[KTOP];
  __shared__ int s_cnt;
  __shared__ float s_sthr;
  if (tid == 0) { s_cnt = 0; s_sthr = 0.f; }
  __syncthreads();

  const float4 t = ((const float4*)targets)[b * MQ + m];
  const float x21 = t.x, y21 = t.y, x22 = t.z, y22 = t.w;
  const float w2 = x22 - x21, h2 = y22 - y21;
  const float atan_t = atanf(w2 * frcp(h2 + EPSQ));
  const float area2 = w2 * h2;
  const float sumx2 = x21 + x22, sumy2 = y21 + y22;
  const float CPI = 4.0f / (float)(M_PI * M_PI);

  const int chunkN = (N + CH - 1) / CH;
  const int n0 = chunk * chunkN;
  const int n1 = min(N, n0 + chunkN);
  float sthr = 0.f;

  const float4* pbb = pb + (size_t)b * N;
  const float* pab = patan + (size_t)b * N;

  for (int basei = n0; basei < n1; basei += SSEG * 256) {
#pragma unroll
    for (int s = 0; s < SSEG; ++s) {
      int n = basei + s * 256 + tid;
      if (n < n1) {
        float4 p = pbb[n];
        float pa = pab[n];
        float x11 = p.x, y11 = p.y, x12 = p.z, y12 = p.w;
        float w1 = x12 - x11, h1 = y12 - y11;
        float iw = fmaxf(fminf(x12, x22) - fmaxf(x11, x21), 0.f);
        float ih = fmaxf(fminf(y12, y22) - fmaxf(y11, y21), 0.f);
        float inter = iw * ih;
        float uni = w1 * h1 + area2 - inter + EPSQ;
        float iou = inter * frcp(uni);
        float cw = fmaxf(x12, x22) - fminf(x11, x21);
        float ch = fmaxf(y12, y22) - fminf(y11, y21);
        float c2 = cw * cw + ch * ch + EPSQ;
        float dx = sumx2 - x11 - x12;
        float dy = sumy2 - y11 - y12;
        float rho2 = (dx * dx + dy * dy) * 0.25f;
        float da = atan_t - pa;
        float v = CPI * da * da;
        float alpha = v * frcp(v - iou + 1.f + EPSQ);
        float ciou = iou - rho2 * frcp(c2) - alpha * v;
        if (ciou > sthr) {
          int slot = atomicAdd(&s_cnt, 1);
          s_bv[slot] = ciou;
          s_bi[slot] = n;
        }
      }
    }
    __syncthreads();          // pushes visible
    int c = s_cnt;            // uniform snapshot
    __syncthreads();          // everyone snapshotted before any mutation
    if (c > TRIG) {
      select_top10(s_bv, s_bi, s_winv, s_wini, &s_cnt, &s_sthr, c, tid);
      __syncthreads();
    }
    sthr = s_sthr;
  }

  int c = s_cnt;
  if (c > KTOP) {
    select_top10(s_bv, s_bi, s_winv, s_wini, &s_cnt, &s_sthr, c, tid);
    __syncthreads();
    c = KTOP;
  }
  const int out_base = bm * (CH * KTOP) + chunk * KTOP;
  if (tid < KTOP) {
    float v = (tid < c) ? s_bv[tid] : 0.f;
    int ix = (tid < c) ? s_bi[tid] : 0;
    cand_v[out_base + tid] = v;
    cand_i[out_base + tid] = ix;
  }
}

// ---------------- topk phase 2: rank 40 candidates per (b,m), scatter-max ----------------
__global__ __launch_bounds__(64) void topk2_kernel(
    const float* __restrict__ cand_v, const int* __restrict__ cand_i,
    unsigned int* __restrict__ iou_bits, float* __restrict__ fin_v,
    int* __restrict__ fin_i, int N) {
  const int bm = blockIdx.x;
  const int b = bm >> 6;
  const int tid = threadIdx.x;
  const int NC = CH * KTOP;  // 40
  __shared__ float sv[NC];
  __shared__ int si[NC];
  if (tid < KTOP) { fin_v[bm * KTOP + tid] = 0.f; fin_i[bm * KTOP + tid] = 0; }
  if (tid < NC) {
    sv[tid] = cand_v[bm * NC + tid];
    si[tid] = cand_i[bm * NC + tid];
  }
  __syncthreads();
  if (tid < NC) {
    float v = sv[tid];
    if (v > 0.f) {
      int rank = 0;
#pragma unroll
      for (int i2 = 0; i2 < NC; ++i2)
        rank += (sv[i2] > v) || (sv[i2] == v && i2 < tid);
      if (rank < KTOP) {
        atomicMax(&iou_bits[(size_t)b * N + si[tid]], __float_as_uint(v));
        fin_v[bm * KTOP + rank] = v;
        fin_i[bm * KTOP + rank] = si[tid];
      }
    }
  }
}

// ---------------- fixup: winner-claim corrections + elected finalize ----------------
__global__ __launch_bounds__(256) void fixup_kernel(
    const float* __restrict__ fin_v, const int* __restrict__ fin_i,
    const unsigned int* __restrict__ iou_bits,
    const float* __restrict__ scores, float* __restrict__ acc,
    float* __restrict__ out, int N, int nblocks) {
  const int tid = threadIdx.x;
  const int e = blockIdx.x * 256 + tid;
  const int TOT = BQ * MQ * KTOP;
  if (e < TOT) {
    int b = e / (MQ * KTOP);
    float v = fin_v[e];
    if (v > 0.f) {
      int ix = fin_i[e];
      if (iou_bits[(size_t)b * N + ix] == __float_as_uint(v)) {
        // this entry is the scatter-max winner for its anchor
        atomicAdd(&acc[b * 4 + 0], 1.f - v);
        atomicAdd(&acc[b * 4 + 1], 1.f);
        atomicAdd(&acc[b * 4 + 2], -scores[(size_t)b * N + ix] * v);
      }
    }
  }
  __threadfence();
  __syncthreads();
  if (tid == 0) {
    unsigned int* cnt = (unsigned int*)(acc + 32);
    unsigned int prev = atomicAdd(cnt, 1u);
    if (prev == (unsigned int)(nblocks - 1)) {
      float box = 0.f, obj = 0.f;
      for (int bb = 0; bb < BQ; ++bb) {
        float sb = __hip_atomic_load(&acc[bb * 4 + 0], __ATOMIC_RELAXED,
                                     __HIP_MEMORY_SCOPE_AGENT);
        float np = __hip_atomic_load(&acc[bb * 4 + 1], __ATOMIC_RELAXED,
                                     __HIP_MEMORY_SCOPE_AGENT);
        float sc = __hip_atomic_load(&acc[bb * 4 + 2], __ATOMIC_RELAXED,
                                     __HIP_MEMORY_SCOPE_AGENT);
        box += (np > 0.f) ? sb * frcp(fmaxf(np, 1.f)) : 0.f;
        obj += sc / (float)N;
      }
      out[0] = (7.5f * box + obj) / (float)BQ;
      out[1] = box;
      out[2] = obj;
    }
  }
}

extern "C" void kernel_launch(void* const* d_in, const int* in_sizes, int n_in,
                              void* d_out, int out_size, void* d_ws, size_t ws_size,
                              hipStream_t stream) {
  const float* boxes = (const float*)d_in[0];
  const float* scores = (const float*)d_in[1];
  const float* targets = (const float*)d_in[2];
  float* out = (float*)d_out;
  const int N = in_sizes[1] / BQ;  // scores is [B, N]

  char* ws = (char*)d_ws;
  size_t pb_bytes = (size_t)BQ * N * 4 * sizeof(float);
  size_t patan_bytes = (size_t)BQ * N * sizeof(float);
  size_t iou_bytes = (size_t)BQ * N * sizeof(unsigned int);
  size_t acc_bytes = 64 * sizeof(float);
  size_t cand_bytes = (size_t)BQ * MQ * CH * KTOP * sizeof(float);
  size_t fin_bytes = (size_t)BQ * MQ * KTOP * sizeof(float);

  float* pb = (float*)ws;                      ws += pb_bytes;
  float* patan = (float*)ws;                   ws += patan_bytes;
  unsigned int* iou_bits = (unsigned int*)ws;  ws += iou_bytes;
  float* acc = (float*)ws;                     ws += acc_bytes;
  float* cand_v = (float*)ws;                  ws += cand_bytes;
  int* cand_i = (int*)ws;                      ws += cand_bytes;
  float* fin_v = (float*)ws;                   ws += fin_bytes;
  int* fin_i = (int*)ws;

  hipMemsetAsync(acc, 0, acc_bytes, stream);

  int total = BQ * N;
  decode_kernel<<<(total + 255) / 256, 256, 0, stream>>>(boxes, scores, pb,
                                                         patan, iou_bits, acc, N);
  topk1_kernel<<<BQ * MQ * CH, 256, 0, stream>>>((const float4*)pb, patan,
                                                 targets, cand_v, cand_i, N);
  topk2_kernel<<<BQ * MQ, 64, 0, stream>>>(cand_v, cand_i, iou_bits, fin_v,
                                           fin_i, N);
  const int TOT = BQ * MQ * KTOP;
  const int nblocks = (TOT + 255) / 256;
  fixup_kernel<<<nblocks, 256, 0, stream>>>(fin_v, fin_i, iou_bits, scores, acc,
                                            out, N, nblocks);
}

// Round 4
// 168.959 us; speedup vs baseline: 1.2074x; 1.2074x over previous
//
#include <hip/hip_runtime.h>
#include <math.h>

#define BQ 8
#define MQ 64
#define REGMAX 16
#define KTOP 10
#define EPSQ 1e-7f
#define SSEG 4
#define TRIG 256
#define CBUF (TRIG + SSEG * 256 + 16)  // max fill = TRIG + SSEG*256 = 1280 < 1296

__device__ __forceinline__ float frcp(float x) { return __builtin_amdgcn_rcpf(x); }

// state layout in ws (one 256B memset):
//   float acc[32]   : per-batch {sum(1-v), npos, bce_sum, pad}
//   int   cnt[8]    : per-batch compacted count      (offset 32 floats)
//   int   done[8]   : per-batch completed (b,m) blocks (offset 40)
//   int   done_all  : completed batch-cleanups         (offset 48)

// ---------------- decode: DFL softmax EV + screen + compact + bce(s,0) + iou zero ----------------
__global__ __launch_bounds__(256) void decode_kernel(
    const float* __restrict__ boxes, const float* __restrict__ scores,
    float4* __restrict__ pbc, float2* __restrict__ atc,
    unsigned int* __restrict__ iou_bits, float* __restrict__ state,
    int N, int bpb) {
  const int tid = threadIdx.x;
  const int b = blockIdx.x / bpb;
  const int n = (blockIdx.x - b * bpb) * 256 + tid;
  float* acc = state;
  int* cnt = (int*)(state + 32);

  __shared__ float4 s_v4[256];
  __shared__ float2 s_ai[256];
  __shared__ int s_cnt, s_base;
  __shared__ float r0[256];
  if (tid == 0) s_cnt = 0;
  __syncthreads();

  float bce0 = 0.f;
  if (n < N) {
    const size_t i = (size_t)b * N + n;
    iou_bits[i] = 0u;
    float sc = scores[i];
    bce0 = fmaxf(sc, 0.f) + log1pf(__expf(-fabsf(sc)));
    const float* base = boxes + (size_t)b * (4 * REGMAX) * N + n;
    float out[4];
#pragma unroll
    for (int k = 0; k < 4; ++k) {
      float x[REGMAX];
#pragma unroll
      for (int r = 0; r < REGMAX; ++r)
        x[r] = base[(size_t)(k * REGMAX + r) * N];
      float mx = x[0];
#pragma unroll
      for (int r = 1; r < REGMAX; ++r) mx = fmaxf(mx, x[r]);
      float s = 0.f, ws = 0.f;
#pragma unroll
      for (int r = 0; r < REGMAX; ++r) {
        float e = __expf(x[r] - mx);
        s += e;
        ws += (float)r * e;
      }
      out[k] = ws * frcp(s);
    }
    float w1 = out[2] - out[0], h1 = out[3] - out[1];
    if (w1 > 0.f && h1 > 0.f) {  // else ciou <= 0 for every target: never contributes
      int slot = atomicAdd(&s_cnt, 1);
      s_v4[slot] = make_float4(out[0], out[1], out[2], out[3]);
      s_ai[slot] = make_float2(atanf(w1 * frcp(h1 + EPSQ)), __int_as_float(n));
    }
  }
  __syncthreads();
  const int bc = s_cnt;
  if (tid == 0) s_base = atomicAdd(&cnt[b], bc);
  __syncthreads();
  const int basei = s_base;
  for (int sl = tid; sl < bc; sl += 256) {
    pbc[(size_t)b * N + basei + sl] = s_v4[sl];
    atc[(size_t)b * N + basei + sl] = s_ai[sl];
  }
  r0[tid] = bce0;
  __syncthreads();
  for (int s = 128; s > 0; s >>= 1) {
    if (tid < s) r0[tid] += r0[tid + s];
    __syncthreads();
  }
  if (tid == 0) atomicAdd(&acc[b * 4 + 2], r0[0]);
}

// ---------------- exact top-10 of LDS buffer (wave 0 only) ----------------
__device__ __forceinline__ void select_top10(
    float* s_bv, int* s_bi, float* s_winv, int* s_wini,
    int* s_cnt, float* s_sthr, int c, int tid) {
  if (tid < 64) {
    for (int r = 0; r < KTOP; ++r) {
      float bv = 0.f;
      int bs = 0xffff;
      for (int sl = tid; sl < c; sl += 64) {
        float v = s_bv[sl];
        if (v > bv) { bv = v; bs = sl; }
      }
      unsigned long long key =
          ((unsigned long long)__float_as_uint(bv) << 32) | (unsigned int)bs;
#pragma unroll
      for (int d = 1; d < 64; d <<= 1) {
        unsigned long long o = __shfl_xor(key, d, 64);
        if (o > key) key = o;
      }
      if (tid == 0) {
        float wv = __uint_as_float((unsigned int)(key >> 32));
        int ws = (int)(key & 0xffffu);
        s_winv[r] = wv;
        if (wv > 0.f && ws != 0xffff) {
          s_wini[r] = s_bi[ws];
          s_bv[ws] = 0.f;
        } else {
          s_wini[r] = 0;
        }
      }
    }
    if (tid < KTOP) { s_bv[tid] = s_winv[tid]; s_bi[tid] = s_wini[tid]; }
    if (tid == 0) { *s_cnt = KTOP; *s_sthr = s_winv[KTOP - 1]; }
  }
}

// ---------------- topk_all: one block per (b,m); scatter + elected cleanup + finalize ----------------
__global__ __launch_bounds__(256) void topk_all_kernel(
    const float4* __restrict__ pbc, const float2* __restrict__ atc,
    const float* __restrict__ targets, const float* __restrict__ scores,
    unsigned int* __restrict__ iou_bits, unsigned int* __restrict__ fin_v,
    int* __restrict__ fin_i, float* __restrict__ state,
    float* __restrict__ out, int N) {
  const int bm = blockIdx.x;
  const int b = bm >> 6;
  const int m = bm & 63;
  const int tid = threadIdx.x;
  float* acc = state;
  int* cnt = (int*)(state + 32);
  int* done = (int*)(state + 40);
  int* done_all = (int*)(state + 48);

  __shared__ float s_bv[CBUF];
  __shared__ int s_bi[CBUF];
  __shared__ float s_winv[KTOP];
  __shared__ int s_wini[KTOP];
  __shared__ int s_cnt, s_flag, s_flag2;
  __shared__ float s_sthr;
  if (tid == 0) { s_cnt = 0; s_sthr = 0.f; }
  __syncthreads();

  const float4 t = ((const float4*)targets)[b * MQ + m];
  const float x21 = t.x, y21 = t.y, x22 = t.z, y22 = t.w;
  const float w2 = x22 - x21, h2 = y22 - y21;
  const float atan_t = atanf(w2 * frcp(h2 + EPSQ));
  const float area2 = w2 * h2;
  const float sumx2 = x21 + x22, sumy2 = y21 + y22;
  const float CPI = 4.0f / (float)(M_PI * M_PI);

  const int cntb = cnt[b];
  float sthr = 0.f;
  const float4* pbb = pbc + (size_t)b * N;
  const float2* pab = atc + (size_t)b * N;

  for (int basei = 0; basei < cntb; basei += SSEG * 256) {
#pragma unroll
    for (int s = 0; s < SSEG; ++s) {
      int j = basei + s * 256 + tid;
      if (j < cntb) {
        float4 p = pbb[j];
        float2 ai = pab[j];
        float x11 = p.x, y11 = p.y, x12 = p.z, y12 = p.w;
        float w1 = x12 - x11, h1 = y12 - y11;
        float iw = fmaxf(fminf(x12, x22) - fmaxf(x11, x21), 0.f);
        float ih = fmaxf(fminf(y12, y22) - fmaxf(y11, y21), 0.f);
        float inter = iw * ih;
        float uni = w1 * h1 + area2 - inter + EPSQ;
        float iou = inter * frcp(uni);
        float cw = fmaxf(x12, x22) - fminf(x11, x21);
        float ch = fmaxf(y12, y22) - fminf(y11, y21);
        float c2 = cw * cw + ch * ch + EPSQ;
        float dx = sumx2 - x11 - x12;
        float dy = sumy2 - y11 - y12;
        float rho2 = (dx * dx + dy * dy) * 0.25f;
        float da = atan_t - ai.x;
        float v = CPI * da * da;
        float alpha = v * frcp(v - iou + 1.f + EPSQ);
        float ciou = iou - rho2 * frcp(c2) - alpha * v;
        if (ciou > sthr) {
          int slot = atomicAdd(&s_cnt, 1);
          s_bv[slot] = ciou;
          s_bi[slot] = __float_as_int(ai.y);  // original anchor index
        }
      }
    }
    __syncthreads();
    int c = s_cnt;
    __syncthreads();
    if (c > TRIG) {
      select_top10(s_bv, s_bi, s_winv, s_wini, &s_cnt, &s_sthr, c, tid);
      __syncthreads();
    }
    sthr = s_sthr;
  }

  int c = s_cnt;
  if (c > KTOP) {
    select_top10(s_bv, s_bi, s_winv, s_wini, &s_cnt, &s_sthr, c, tid);
    __syncthreads();
    c = KTOP;
  }

  // publish top-10 + scatter-max
  if (tid < KTOP) {
    float v = (tid < c) ? s_bv[tid] : 0.f;
    int ix = (tid < c) ? s_bi[tid] : 0;
    if (v > 0.f) atomicMax(&iou_bits[(size_t)b * N + ix], __float_as_uint(v));
    __hip_atomic_store(&fin_v[bm * KTOP + tid], __float_as_uint(v),
                       __ATOMIC_RELAXED, __HIP_MEMORY_SCOPE_AGENT);
    __hip_atomic_store(&fin_i[bm * KTOP + tid], ix, __ATOMIC_RELAXED,
                       __HIP_MEMORY_SCOPE_AGENT);
    __threadfence();
  }
  __syncthreads();
  if (tid == 0) {
    __threadfence();
    int prev = __hip_atomic_fetch_add(&done[b], 1, __ATOMIC_ACQ_REL,
                                      __HIP_MEMORY_SCOPE_AGENT);
    s_flag = (prev == MQ - 1);
  }
  __syncthreads();

  if (s_flag) {  // last (b,m) block of batch b: apply winner corrections
    __threadfence();
    for (int e = tid; e < MQ * KTOP; e += 256) {
      int slot = b * (MQ * KTOP) + e;
      unsigned int vb = __hip_atomic_load(&fin_v[slot], __ATOMIC_RELAXED,
                                          __HIP_MEMORY_SCOPE_AGENT);
      float v = __uint_as_float(vb);
      if (v > 0.f) {
        int ix = __hip_atomic_load(&fin_i[slot], __ATOMIC_RELAXED,
                                   __HIP_MEMORY_SCOPE_AGENT);
        unsigned int cur = __hip_atomic_load(&iou_bits[(size_t)b * N + ix],
                                             __ATOMIC_RELAXED,
                                             __HIP_MEMORY_SCOPE_AGENT);
        if (cur == vb) {  // this entry is the scatter-max winner for anchor ix
          atomicAdd(&acc[b * 4 + 0], 1.f - v);
          atomicAdd(&acc[b * 4 + 1], 1.f);
          atomicAdd(&acc[b * 4 + 2], -scores[(size_t)b * N + ix] * v);
        }
      }
    }
    __threadfence();
    __syncthreads();
    if (tid == 0) {
      int prev = __hip_atomic_fetch_add(done_all, 1, __ATOMIC_ACQ_REL,
                                        __HIP_MEMORY_SCOPE_AGENT);
      s_flag2 = (prev == BQ - 1);
    }
    __syncthreads();
    if (s_flag2 && tid == 0) {  // very last cleanup: finalize
      __threadfence();
      float box = 0.f, obj = 0.f;
      for (int bb = 0; bb < BQ; ++bb) {
        float sb = __hip_atomic_load(&acc[bb * 4 + 0], __ATOMIC_RELAXED,
                                     __HIP_MEMORY_SCOPE_AGENT);
        float np = __hip_atomic_load(&acc[bb * 4 + 1], __ATOMIC_RELAXED,
                                     __HIP_MEMORY_SCOPE_AGENT);
        float sc = __hip_atomic_load(&acc[bb * 4 + 2], __ATOMIC_RELAXED,
                                     __HIP_MEMORY_SCOPE_AGENT);
        box += (np > 0.f) ? sb / fmaxf(np, 1.f) : 0.f;
        obj += sc / (float)N;
      }
      out[0] = (7.5f * box + obj) / (float)BQ;
      out[1] = box;
      out[2] = obj;
    }
  }
}

extern "C" void kernel_launch(void* const* d_in, const int* in_sizes, int n_in,
                              void* d_out, int out_size, void* d_ws, size_t ws_size,
                              hipStream_t stream) {
  const float* boxes = (const float*)d_in[0];
  const float* scores = (const float*)d_in[1];
  const float* targets = (const float*)d_in[2];
  float* out = (float*)d_out;
  const int N = in_sizes[1] / BQ;  // scores is [B, N]

  char* ws = (char*)d_ws;
  size_t pbc_bytes = (size_t)BQ * N * sizeof(float4);
  size_t atc_bytes = (size_t)BQ * N * sizeof(float2);
  size_t iou_bytes = (size_t)BQ * N * sizeof(unsigned int);
  size_t fin_bytes = (size_t)BQ * MQ * KTOP * sizeof(unsigned int);

  float4* pbc = (float4*)ws;                   ws += pbc_bytes;
  float2* atc = (float2*)ws;                   ws += atc_bytes;
  unsigned int* iou_bits = (unsigned int*)ws;  ws += iou_bytes;
  unsigned int* fin_v = (unsigned int*)ws;     ws += fin_bytes;
  int* fin_i = (int*)ws;                       ws += fin_bytes;
  float* state = (float*)ws;                   // 256 B

  hipMemsetAsync(state, 0, 256, stream);

  const int bpb = (N + 255) / 256;
  decode_kernel<<<BQ * bpb, 256, 0, stream>>>(boxes, scores, pbc, atc,
                                              iou_bits, state, N, bpb);
  topk_all_kernel<<<BQ * MQ, 256, 0, stream>>>(pbc, atc, targets, scores,
                                               iou_bits, fin_v, fin_i, state,
                                               out, N);
}